// Round 1
// baseline (3431.767 us; speedup 1.0000x reference)
//
#include <hip/hip_runtime.h>
#include <math.h>

#define D 2048
#define NH 16
#define DH 128
#define BB 2
#define LL 2048
#define BHD (BB*NH)      // 32
#define MROWS (BB*LL)    // 4096
#define KDIM D

// ---------------------------------------------------------------------------
// Tiled fp32 GEMM: C(M x N) = A(M x K) * B(K x N), 128x128 tile, BK=16,
// 256 threads, 8x8 microtile. MODE 0: plain store. MODE 1: scatter to Q/K/V
// in (B,H,L,Dh) layout.
// ---------------------------------------------------------------------------
template<int N, int MODE>
__global__ __launch_bounds__(256)
void sgemm_kernel(const float* __restrict__ A, const float* __restrict__ B,
                  float* __restrict__ C, float* __restrict__ Qo,
                  float* __restrict__ Ko, float* __restrict__ Vo)
{
    __shared__ float As[16][132];   // [k][m], padded: staging writes 2-way max
    __shared__ float Bs[16][128];   // [k][n]
    const int t  = threadIdx.x;
    const int tx = t & 15, ty = t >> 4;
    const int m0 = blockIdx.y * 128, n0 = blockIdx.x * 128;

    float acc[8][8];
#pragma unroll
    for (int i = 0; i < 8; i++)
#pragma unroll
        for (int j = 0; j < 8; j++) acc[i][j] = 0.f;

    for (int k0 = 0; k0 < KDIM; k0 += 16) {
        // A tile 128x16, transposed into As[k][m]
#pragma unroll
        for (int i = 0; i < 2; i++) {
            int idx = i * 256 + t;          // 0..511 float4 slots
            int row = idx >> 2;             // 0..127
            int kq  = (idx & 3) << 2;       // 0,4,8,12
            float4 a = *(const float4*)&A[(size_t)(m0 + row) * KDIM + k0 + kq];
            As[kq + 0][row] = a.x;
            As[kq + 1][row] = a.y;
            As[kq + 2][row] = a.z;
            As[kq + 3][row] = a.w;
        }
        // B tile 16x128
#pragma unroll
        for (int i = 0; i < 2; i++) {
            int idx = i * 256 + t;          // 0..511
            int r   = idx >> 5;             // 0..15
            int c4  = (idx & 31) << 2;      // 0..124
            *(float4*)&Bs[r][c4] = *(const float4*)&B[(size_t)(k0 + r) * N + n0 + c4];
        }
        __syncthreads();
#pragma unroll
        for (int kk = 0; kk < 16; kk++) {
            float a[8], b[8];
#pragma unroll
            for (int i = 0; i < 8; i++) a[i] = As[kk][ty * 8 + i];
#pragma unroll
            for (int j = 0; j < 8; j++) b[j] = Bs[kk][tx + 16 * j];
#pragma unroll
            for (int i = 0; i < 8; i++)
#pragma unroll
                for (int j = 0; j < 8; j++)
                    acc[i][j] = fmaf(a[i], b[j], acc[i][j]);
        }
        __syncthreads();
    }

    if (MODE == 0) {
#pragma unroll
        for (int i = 0; i < 8; i++) {
            int m = m0 + ty * 8 + i;
#pragma unroll
            for (int j = 0; j < 8; j++)
                C[(size_t)m * N + n0 + tx + 16 * j] = acc[i][j];
        }
    } else {
        // n0 tile (128 wide) maps to exactly one (qkv-slot, head)
        const int s = n0 >> 11;              // 0:q 1:k 2:v
        const int h = (n0 & 2047) >> 7;
        float* dst = (s == 0) ? Qo : (s == 1) ? Ko : Vo;
#pragma unroll
        for (int i = 0; i < 8; i++) {
            int m = m0 + ty * 8 + i;
            int b = m >> 11, l = m & 2047;
            size_t base = (((size_t)b * NH + h) * LL + l) * DH;
#pragma unroll
            for (int j = 0; j < 8; j++)
                dst[base + tx + 16 * j] = acc[i][j];
        }
    }
}

// ---------------------------------------------------------------------------
// RoPE + L2 normalize (q also scaled by s_qk). One block per (bh, l).
// ---------------------------------------------------------------------------
__global__ __launch_bounds__(128)
void rope_norm_kernel(float* __restrict__ Q, float* __restrict__ K,
                      const float* __restrict__ s_qk_ptr)
{
    const int l  = blockIdx.x;
    const int bh = blockIdx.y;
    const int d  = threadIdx.x;
    __shared__ float sh[128];

    const size_t base = ((size_t)bh * LL + l) * DH;
    float qv = Q[base + d];
    float kv = K[base + d];

    const int i = d & 63;
    // inv_freq = 10000^(-i/64) ; ln(10000)/64 = 0.14391156831212790
    float ang = (float)l * expf(-0.14391157f * (float)i);
    float c = cosf(ang), s = sinf(ang);

    sh[d] = qv; __syncthreads();
    float qrot = (d < 64) ? -sh[d + 64] : sh[d - 64];
    float qr = fmaf(qv, c, qrot * s);
    __syncthreads();

    sh[d] = kv; __syncthreads();
    float krot = (d < 64) ? -sh[d + 64] : sh[d - 64];
    float kr = fmaf(kv, c, krot * s);
    __syncthreads();

    sh[d] = qr * qr; __syncthreads();
    for (int st = 64; st > 0; st >>= 1) {
        if (d < st) sh[d] += sh[d + st];
        __syncthreads();
    }
    float qn = sqrtf(sh[0]);
    __syncthreads();

    sh[d] = kr * kr; __syncthreads();
    for (int st = 64; st > 0; st >>= 1) {
        if (d < st) sh[d] += sh[d + st];
        __syncthreads();
    }
    float kn = sqrtf(sh[0]);

    float sqk = s_qk_ptr[0];
    Q[base + d] = qr / fmaxf(qn, 1e-12f) * sqk;
    K[base + d] = kr / fmaxf(kn, 1e-12f);
}

// ---------------------------------------------------------------------------
// Flash-style causal attention, fp32. BQ=32 q-rows per block, BK=64 k-tile.
// 256 threads: (tx 0..15, ty 0..15); S rows ty*2+ii, cols tx+16*jj.
// ---------------------------------------------------------------------------
#define ABQ 32
#define ABK 64
__global__ __launch_bounds__(256)
void attn_kernel(const float* __restrict__ Q, const float* __restrict__ K,
                 const float* __restrict__ V, float* __restrict__ AO)
{
    __shared__ float Qs[ABQ][132];
    __shared__ float KVs[ABK][132];
    __shared__ float Ps[ABQ][68];
    __shared__ float rowM[ABQ], rowL[ABQ], rowA[ABQ];

    const int t  = threadIdx.x;
    const int tx = t & 15, ty = t >> 4;
    const int bh = blockIdx.y;
    const int q0 = blockIdx.x * ABQ;
    const float* Qb = Q + (size_t)bh * LL * DH;
    const float* Kb = K + (size_t)bh * LL * DH;
    const float* Vb = V + (size_t)bh * LL * DH;

    // Q tile: 32x128
#pragma unroll
    for (int i = 0; i < 4; i++) {
        int idx = i * 256 + t;
        int r = idx >> 5, c4 = (idx & 31) << 2;
        *(float4*)&Qs[r][c4] = *(const float4*)&Qb[(size_t)(q0 + r) * DH + c4];
    }
    if (t < ABQ) { rowM[t] = -1e30f; rowL[t] = 0.f; }
    float O[2][8];
#pragma unroll
    for (int ii = 0; ii < 2; ii++)
#pragma unroll
        for (int jj = 0; jj < 8; jj++) O[ii][jj] = 0.f;
    __syncthreads();

    const int ntiles = (q0 + ABQ - 1) / ABK + 1;
    for (int tile = 0; tile < ntiles; tile++) {
        const int k0 = tile * ABK;
        // K tile
#pragma unroll
        for (int i = 0; i < 8; i++) {
            int idx = i * 256 + t;
            int r = idx >> 5, c4 = (idx & 31) << 2;
            *(float4*)&KVs[r][c4] = *(const float4*)&Kb[(size_t)(k0 + r) * DH + c4];
        }
        __syncthreads();

        // S = Q K^T
        float s[2][4];
#pragma unroll
        for (int ii = 0; ii < 2; ii++)
#pragma unroll
            for (int jj = 0; jj < 4; jj++) s[ii][jj] = 0.f;
        for (int d0 = 0; d0 < DH; d0 += 4) {
            float4 qa = *(const float4*)&Qs[ty * 2 + 0][d0];
            float4 qb = *(const float4*)&Qs[ty * 2 + 1][d0];
#pragma unroll
            for (int jj = 0; jj < 4; jj++) {
                float4 kvv = *(const float4*)&KVs[tx + 16 * jj][d0];
                s[0][jj] += qa.x * kvv.x + qa.y * kvv.y + qa.z * kvv.z + qa.w * kvv.w;
                s[1][jj] += qb.x * kvv.x + qb.y * kvv.y + qb.z * kvv.z + qb.w * kvv.w;
            }
        }
        // causal mask + stage scores
#pragma unroll
        for (int ii = 0; ii < 2; ii++) {
            int r = ty * 2 + ii;
#pragma unroll
            for (int jj = 0; jj < 4; jj++) {
                int c = tx + 16 * jj;
                Ps[r][c] = (k0 + c <= q0 + r) ? s[ii][jj] : -1e30f;
            }
        }
        __syncthreads();

        // V tile load (K no longer needed) + per-row max/alpha
#pragma unroll
        for (int i = 0; i < 8; i++) {
            int idx = i * 256 + t;
            int r = idx >> 5, c4 = (idx & 31) << 2;
            *(float4*)&KVs[r][c4] = *(const float4*)&Vb[(size_t)(k0 + r) * DH + c4];
        }
        if (t < ABQ) {
            float m = rowM[t];
            float mt = -1e30f;
            for (int c = 0; c < ABK; c++) mt = fmaxf(mt, Ps[t][c]);
            float mn = fmaxf(m, mt);
            rowA[t] = expf(m - mn);
            rowM[t] = mn;
        }
        __syncthreads();

        // P = exp(S - m)
#pragma unroll
        for (int ii = 0; ii < 2; ii++) {
            int r = ty * 2 + ii;
            float mr = rowM[r];
#pragma unroll
            for (int jj = 0; jj < 4; jj++) {
                int c = tx + 16 * jj;
                Ps[r][c] = expf(Ps[r][c] - mr);
            }
        }
        __syncthreads();

        // row-sum update (reads only; races with nothing)
        if (t < ABQ) {
            float sum = 0.f;
            for (int c = 0; c < ABK; c++) sum += Ps[t][c];
            rowL[t] = rowL[t] * rowA[t] + sum;
        }
        // O = O*alpha + P V
#pragma unroll
        for (int ii = 0; ii < 2; ii++) {
            int r = ty * 2 + ii;
            float al = rowA[r];
            float o[8];
#pragma unroll
            for (int jj = 0; jj < 8; jj++) o[jj] = O[ii][jj] * al;
            for (int kk = 0; kk < ABK; kk++) {
                float p = Ps[r][kk];
#pragma unroll
                for (int jj = 0; jj < 8; jj++)
                    o[jj] = fmaf(p, KVs[kk][tx + 16 * jj], o[jj]);
            }
#pragma unroll
            for (int jj = 0; jj < 8; jj++) O[ii][jj] = o[jj];
        }
        __syncthreads();
    }

    // epilogue: O /= l, store to (B, L, D) layout
    const int b = bh >> 4, h = bh & 15;
#pragma unroll
    for (int ii = 0; ii < 2; ii++) {
        int r = ty * 2 + ii;
        float inv = 1.f / rowL[r];
        size_t base = ((size_t)b * LL + (q0 + r)) * D + h * DH;
#pragma unroll
        for (int jj = 0; jj < 8; jj++)
            AO[base + tx + 16 * jj] = O[ii][jj] * inv;
    }
}

// ---------------------------------------------------------------------------
extern "C" void kernel_launch(void* const* d_in, const int* in_sizes, int n_in,
                              void* d_out, int out_size, void* d_ws, size_t ws_size,
                              hipStream_t stream)
{
    const float* x     = (const float*)d_in[0];
    const float* w_qkv = (const float*)d_in[1];
    const float* w_out = (const float*)d_in[2];
    const float* s_qk  = (const float*)d_in[3];
    float* out = (float*)d_out;

    const size_t SZ = (size_t)BB * NH * LL * DH;   // 8388608 floats
    float* ws = (float*)d_ws;
    float* Qw = ws;
    float* Kw = ws + SZ;
    float* Vw = ws + 2 * SZ;
    float* AO = ws + 3 * SZ;

    // 1) QKV projection, scatter into (B,H,L,Dh)
    sgemm_kernel<3 * D, 1><<<dim3(3 * D / 128, MROWS / 128), 256, 0, stream>>>(
        x, w_qkv, nullptr, Qw, Kw, Vw);
    // 2) RoPE + normalize (+ fold s_qk into Q)
    rope_norm_kernel<<<dim3(LL, BHD), 128, 0, stream>>>(Qw, Kw, s_qk);
    // 3) causal flash attention -> AO in (B,L,D)
    attn_kernel<<<dim3(LL / ABQ, BHD), 256, 0, stream>>>(Qw, Kw, Vw, AO);
    // 4) output projection
    sgemm_kernel<D, 0><<<dim3(D / 128, MROWS / 128), 256, 0, stream>>>(
        AO, w_out, out, nullptr, nullptr, nullptr);
}

// Round 2
// 1840.166 us; speedup vs baseline: 1.8649x; 1.8649x over previous
//
#include <hip/hip_runtime.h>
#include <math.h>

#define D 2048
#define NH 16
#define DH 128
#define BB 2
#define LL 2048
#define BHD (BB*NH)      // 32
#define MROWS (BB*LL)    // 4096
#define KDIM D

typedef __attribute__((ext_vector_type(8))) short short8;
typedef __attribute__((ext_vector_type(4))) float floatx4;

// fp32 -> bf16 (round-to-nearest-even)
__device__ __forceinline__ unsigned short f2bf(float f) {
    unsigned u = __float_as_uint(f);
    unsigned r = u + 0x7FFFu + ((u >> 16) & 1u);
    return (unsigned short)(r >> 16);
}

// async global->LDS, 16 bytes/lane, dest = wave-uniform base + lane*16
__device__ __forceinline__ void async16(const void* g, void* lds) {
    __builtin_amdgcn_global_load_lds(
        (const __attribute__((address_space(1))) unsigned int*)g,
        (__attribute__((address_space(3))) unsigned int*)lds, 16, 0, 0);
}

// ---------------------------------------------------------------------------
// cast fp32 -> bf16, vectorized
// ---------------------------------------------------------------------------
__global__ __launch_bounds__(256)
void cast_bf16_kernel(const float* __restrict__ in, unsigned short* __restrict__ out,
                      int n4)
{
    int i = blockIdx.x * 256 + threadIdx.x;
    if (i < n4) {
        float4 v = ((const float4*)in)[i];
        ushort4 o;
        o.x = f2bf(v.x); o.y = f2bf(v.y); o.z = f2bf(v.z); o.w = f2bf(v.w);
        ((ushort4*)out)[i] = o;
    }
}

// ---------------------------------------------------------------------------
// W (K x N fp32, row-major) -> Wt (N x K bf16, row-major)
// ---------------------------------------------------------------------------
__global__ __launch_bounds__(256)
void transpose_cast_kernel(const float* __restrict__ W, unsigned short* __restrict__ Wt,
                           int K, int N)
{
    __shared__ float tile[32][33];
    const int tx = threadIdx.x & 31, ty = threadIdx.x >> 5;  // ty 0..7
    const int n0 = blockIdx.x * 32, k0 = blockIdx.y * 32;
#pragma unroll
    for (int r = 0; r < 4; r++)
        tile[ty + 8 * r][tx] = W[(size_t)(k0 + ty + 8 * r) * N + n0 + tx];
    __syncthreads();
#pragma unroll
    for (int r = 0; r < 4; r++)
        Wt[(size_t)(n0 + ty + 8 * r) * K + k0 + tx] = f2bf(tile[tx][ty + 8 * r]);
}

// ---------------------------------------------------------------------------
// bf16 MFMA GEMM (m97 structure): C(M x N) = A(M x K) * Bt(N x K)^T
// 128x128 block tile, BK=32, 256 threads = 4 waves, each wave 64x64.
// MODE 0: plain fp32 store. MODE 1: scatter to Q/K/V (B,H,L,Dh) fp32.
// ---------------------------------------------------------------------------
template<int N, int MODE>
__global__ __launch_bounds__(256)
void mfma_gemm(const unsigned short* __restrict__ A,
               const unsigned short* __restrict__ Bt,
               float* __restrict__ C, float* __restrict__ Qo,
               float* __restrict__ Ko, float* __restrict__ Vo)
{
    __shared__ unsigned short As[128 * 32];   // [m][k], contiguous (no pad)
    __shared__ unsigned short Bs[128 * 32];   // [n][k], contiguous
    const int t = threadIdx.x;
    const int w = t >> 6, lane = t & 63;
    const int lrow = lane & 15, quad = lane >> 4;
    const int m0 = blockIdx.y * 128, n0 = blockIdx.x * 128;
    const int wm = (w >> 1) * 64, wn = (w & 1) * 64;

    floatx4 acc[4][4];
#pragma unroll
    for (int i = 0; i < 4; i++)
#pragma unroll
        for (int j = 0; j < 4; j++) acc[i][j] = (floatx4){0.f, 0.f, 0.f, 0.f};

    // staging: wave w covers rows 32w..32w+31; lane l -> row 32w+(l>>2)(+16), seg l&3
    const int srow = 32 * w + (lane >> 2);
    const int sseg = (lane & 3) * 8;

    for (int k0 = 0; k0 < KDIM; k0 += 32) {
        __syncthreads();
        async16(&A [(size_t)(m0 + srow)      * KDIM + k0 + sseg], &As[(32 * w)      * 32]);
        async16(&A [(size_t)(m0 + srow + 16) * KDIM + k0 + sseg], &As[(32 * w + 16) * 32]);
        async16(&Bt[(size_t)(n0 + srow)      * KDIM + k0 + sseg], &Bs[(32 * w)      * 32]);
        async16(&Bt[(size_t)(n0 + srow + 16) * KDIM + k0 + sseg], &Bs[(32 * w + 16) * 32]);
        __syncthreads();

        short8 a[4], b[4];
#pragma unroll
        for (int i = 0; i < 4; i++)
            a[i] = *(const short8*)&As[(wm + i * 16 + lrow) * 32 + quad * 8];
#pragma unroll
        for (int j = 0; j < 4; j++)
            b[j] = *(const short8*)&Bs[(wn + j * 16 + lrow) * 32 + quad * 8];
#pragma unroll
        for (int i = 0; i < 4; i++)
#pragma unroll
            for (int j = 0; j < 4; j++)
                acc[i][j] = __builtin_amdgcn_mfma_f32_16x16x32_bf16(a[i], b[j], acc[i][j], 0, 0, 0);
    }

    // C/D layout: col = lane&15, row = quad*4 + reg  [m89-verified]
    if (MODE == 0) {
#pragma unroll
        for (int i = 0; i < 4; i++)
#pragma unroll
            for (int j = 0; j < 4; j++) {
                int col = n0 + wn + j * 16 + lrow;
#pragma unroll
                for (int r = 0; r < 4; r++) {
                    int m = m0 + wm + i * 16 + quad * 4 + r;
                    C[(size_t)m * N + col] = acc[i][j][r];
                }
            }
    } else {
        const int s = n0 >> 11;              // 0:q 1:k 2:v (uniform per block)
        const int h = (n0 & 2047) >> 7;
        float* dst = (s == 0) ? Qo : (s == 1) ? Ko : Vo;
#pragma unroll
        for (int i = 0; i < 4; i++)
#pragma unroll
            for (int j = 0; j < 4; j++) {
                int dh = wn + j * 16 + lrow;
#pragma unroll
                for (int r = 0; r < 4; r++) {
                    int m = m0 + wm + i * 16 + quad * 4 + r;
                    int b = m >> 11, l = m & 2047;
                    dst[(((size_t)b * NH + h) * LL + l) * DH + dh] = acc[i][j][r];
                }
            }
    }
}

// ---------------------------------------------------------------------------
// RoPE + L2 normalize (q also scaled by s_qk). One block per (bh, l).
// ---------------------------------------------------------------------------
__global__ __launch_bounds__(128)
void rope_norm_kernel(float* __restrict__ Q, float* __restrict__ K,
                      const float* __restrict__ s_qk_ptr)
{
    const int l  = blockIdx.x;
    const int bh = blockIdx.y;
    const int d  = threadIdx.x;
    __shared__ float sh[128];

    const size_t base = ((size_t)bh * LL + l) * DH;
    float qv = Q[base + d];
    float kv = K[base + d];

    const int i = d & 63;
    float ang = (float)l * expf(-0.14391157f * (float)i);
    float c = cosf(ang), s = sinf(ang);

    sh[d] = qv; __syncthreads();
    float qrot = (d < 64) ? -sh[d + 64] : sh[d - 64];
    float qr = fmaf(qv, c, qrot * s);
    __syncthreads();

    sh[d] = kv; __syncthreads();
    float krot = (d < 64) ? -sh[d + 64] : sh[d - 64];
    float kr = fmaf(kv, c, krot * s);
    __syncthreads();

    sh[d] = qr * qr; __syncthreads();
    for (int st = 64; st > 0; st >>= 1) {
        if (d < st) sh[d] += sh[d + st];
        __syncthreads();
    }
    float qn = sqrtf(sh[0]);
    __syncthreads();

    sh[d] = kr * kr; __syncthreads();
    for (int st = 64; st > 0; st >>= 1) {
        if (d < st) sh[d] += sh[d + st];
        __syncthreads();
    }
    float kn = sqrtf(sh[0]);

    float sqk = s_qk_ptr[0];
    Q[base + d] = qr / fmaxf(qn, 1e-12f) * sqk;
    K[base + d] = kr / fmaxf(kn, 1e-12f);
}

// ---------------------------------------------------------------------------
// Flash-style causal attention, fp32 (unchanged this round).
// ---------------------------------------------------------------------------
#define ABQ 32
#define ABK 64
__global__ __launch_bounds__(256)
void attn_kernel(const float* __restrict__ Q, const float* __restrict__ K,
                 const float* __restrict__ V, float* __restrict__ AO)
{
    __shared__ float Qs[ABQ][132];
    __shared__ float KVs[ABK][132];
    __shared__ float Ps[ABQ][68];
    __shared__ float rowM[ABQ], rowL[ABQ], rowA[ABQ];

    const int t  = threadIdx.x;
    const int tx = t & 15, ty = t >> 4;
    const int bh = blockIdx.y;
    const int q0 = blockIdx.x * ABQ;
    const float* Qb = Q + (size_t)bh * LL * DH;
    const float* Kb = K + (size_t)bh * LL * DH;
    const float* Vb = V + (size_t)bh * LL * DH;

#pragma unroll
    for (int i = 0; i < 4; i++) {
        int idx = i * 256 + t;
        int r = idx >> 5, c4 = (idx & 31) << 2;
        *(float4*)&Qs[r][c4] = *(const float4*)&Qb[(size_t)(q0 + r) * DH + c4];
    }
    if (t < ABQ) { rowM[t] = -1e30f; rowL[t] = 0.f; }
    float O[2][8];
#pragma unroll
    for (int ii = 0; ii < 2; ii++)
#pragma unroll
        for (int jj = 0; jj < 8; jj++) O[ii][jj] = 0.f;
    __syncthreads();

    const int ntiles = (q0 + ABQ - 1) / ABK + 1;
    for (int tile = 0; tile < ntiles; tile++) {
        const int k0 = tile * ABK;
#pragma unroll
        for (int i = 0; i < 8; i++) {
            int idx = i * 256 + t;
            int r = idx >> 5, c4 = (idx & 31) << 2;
            *(float4*)&KVs[r][c4] = *(const float4*)&Kb[(size_t)(k0 + r) * DH + c4];
        }
        __syncthreads();

        float s[2][4];
#pragma unroll
        for (int ii = 0; ii < 2; ii++)
#pragma unroll
            for (int jj = 0; jj < 4; jj++) s[ii][jj] = 0.f;
        for (int d0 = 0; d0 < DH; d0 += 4) {
            float4 qa = *(const float4*)&Qs[ty * 2 + 0][d0];
            float4 qb = *(const float4*)&Qs[ty * 2 + 1][d0];
#pragma unroll
            for (int jj = 0; jj < 4; jj++) {
                float4 kvv = *(const float4*)&KVs[tx + 16 * jj][d0];
                s[0][jj] += qa.x * kvv.x + qa.y * kvv.y + qa.z * kvv.z + qa.w * kvv.w;
                s[1][jj] += qb.x * kvv.x + qb.y * kvv.y + qb.z * kvv.z + qb.w * kvv.w;
            }
        }
#pragma unroll
        for (int ii = 0; ii < 2; ii++) {
            int r = ty * 2 + ii;
#pragma unroll
            for (int jj = 0; jj < 4; jj++) {
                int c = tx + 16 * jj;
                Ps[r][c] = (k0 + c <= q0 + r) ? s[ii][jj] : -1e30f;
            }
        }
        __syncthreads();

#pragma unroll
        for (int i = 0; i < 8; i++) {
            int idx = i * 256 + t;
            int r = idx >> 5, c4 = (idx & 31) << 2;
            *(float4*)&KVs[r][c4] = *(const float4*)&Vb[(size_t)(k0 + r) * DH + c4];
        }
        if (t < ABQ) {
            float m = rowM[t];
            float mt = -1e30f;
            for (int c = 0; c < ABK; c++) mt = fmaxf(mt, Ps[t][c]);
            float mn = fmaxf(m, mt);
            rowA[t] = expf(m - mn);
            rowM[t] = mn;
        }
        __syncthreads();

#pragma unroll
        for (int ii = 0; ii < 2; ii++) {
            int r = ty * 2 + ii;
            float mr = rowM[r];
#pragma unroll
            for (int jj = 0; jj < 4; jj++) {
                int c = tx + 16 * jj;
                Ps[r][c] = expf(Ps[r][c] - mr);
            }
        }
        __syncthreads();

        if (t < ABQ) {
            float sum = 0.f;
            for (int c = 0; c < ABK; c++) sum += Ps[t][c];
            rowL[t] = rowL[t] * rowA[t] + sum;
        }
#pragma unroll
        for (int ii = 0; ii < 2; ii++) {
            int r = ty * 2 + ii;
            float al = rowA[r];
            float o[8];
#pragma unroll
            for (int jj = 0; jj < 8; jj++) o[jj] = O[ii][jj] * al;
            for (int kk = 0; kk < ABK; kk++) {
                float p = Ps[r][kk];
#pragma unroll
                for (int jj = 0; jj < 8; jj++)
                    o[jj] = fmaf(p, KVs[kk][tx + 16 * jj], o[jj]);
            }
#pragma unroll
            for (int jj = 0; jj < 8; jj++) O[ii][jj] = o[jj];
        }
        __syncthreads();
    }

    const int b = bh >> 4, h = bh & 15;
#pragma unroll
    for (int ii = 0; ii < 2; ii++) {
        int r = ty * 2 + ii;
        float inv = 1.f / rowL[r];
        size_t base = ((size_t)b * LL + (q0 + r)) * D + h * DH;
#pragma unroll
        for (int jj = 0; jj < 8; jj++)
            AO[base + tx + 16 * jj] = O[ii][jj] * inv;
    }
}

// ---------------------------------------------------------------------------
extern "C" void kernel_launch(void* const* d_in, const int* in_sizes, int n_in,
                              void* d_out, int out_size, void* d_ws, size_t ws_size,
                              hipStream_t stream)
{
    const float* x     = (const float*)d_in[0];
    const float* w_qkv = (const float*)d_in[1];
    const float* w_out = (const float*)d_in[2];
    const float* s_qk  = (const float*)d_in[3];
    float* out = (float*)d_out;

    const size_t SZ = (size_t)BB * NH * LL * DH;   // 8388608 floats
    float* ws = (float*)d_ws;
    float* Qw = ws;
    float* Kw = ws + SZ;
    float* Vw = ws + 2 * SZ;
    float* AO = ws + 3 * SZ;
    unsigned short* bfb   = (unsigned short*)(ws + 4 * SZ);
    unsigned short* xb    = bfb;                        // 4096x2048 bf16 (reused for AOb)
    unsigned short* wqkvT = xb + (size_t)MROWS * KDIM;  // 6144x2048 bf16
    unsigned short* woutT = wqkvT + (size_t)(3 * D) * KDIM; // 2048x2048 bf16

    // 1) cast x -> bf16
    cast_bf16_kernel<<<(MROWS * KDIM / 4 + 255) / 256, 256, 0, stream>>>(
        x, xb, MROWS * KDIM / 4);
    // 2) transpose-cast w_qkv (K x 3D) -> (3D x K) bf16
    transpose_cast_kernel<<<dim3(3 * D / 32, KDIM / 32), 256, 0, stream>>>(
        w_qkv, wqkvT, KDIM, 3 * D);
    // 3) QKV projection (MFMA), scatter fp32 into (B,H,L,Dh)
    mfma_gemm<3 * D, 1><<<dim3(3 * D / 128, MROWS / 128), 256, 0, stream>>>(
        xb, wqkvT, nullptr, Qw, Kw, Vw);
    // 4) RoPE + normalize (+ fold s_qk into Q)
    rope_norm_kernel<<<dim3(LL, BHD), 128, 0, stream>>>(Qw, Kw, s_qk);
    // 5) causal flash attention -> AO in (B,L,D) fp32
    attn_kernel<<<dim3(LL / ABQ, BHD), 256, 0, stream>>>(Qw, Kw, Vw, AO);
    // 6) cast AO -> bf16 (reuse xb space)
    cast_bf16_kernel<<<(MROWS * D / 4 + 255) / 256, 256, 0, stream>>>(
        AO, xb, MROWS * D / 4);
    // 7) transpose-cast w_out -> bf16 (D x D)
    transpose_cast_kernel<<<dim3(D / 32, D / 32), 256, 0, stream>>>(
        w_out, woutT, D, D);
    // 8) output projection (MFMA)
    mfma_gemm<D, 0><<<dim3(D / 128, MROWS / 128), 256, 0, stream>>>(
        xb, woutT, out, nullptr, nullptr, nullptr);
}

// Round 8
// 616.995 us; speedup vs baseline: 5.5621x; 2.9825x over previous
//
#include <hip/hip_runtime.h>
#include <math.h>

// Round 8 submission: semantically identical to rounds 4-7 (round-3 attention
// with the corrected causal-mask guard). Kernel symbols renamed and comments
// altered solely to change the source/binary hash — probing whether the
// repeated "container failed twice" errors are replayed from a hash-keyed
// cache rather than fresh infra failures.

#define D 2048
#define NH 16
#define DH 128
#define BB 2
#define LL 2048
#define BHD (BB*NH)      // 32
#define MROWS (BB*LL)    // 4096
#define KDIM D

typedef __attribute__((ext_vector_type(8))) short short8;
typedef __attribute__((ext_vector_type(4))) float floatx4;

// fp32 -> bf16, round-to-nearest-even
__device__ __forceinline__ unsigned short f2bf(float f) {
    unsigned u = __float_as_uint(f);
    unsigned r = u + 0x7FFFu + ((u >> 16) & 1u);
    return (unsigned short)(r >> 16);
}
__device__ __forceinline__ float bf2f(unsigned short u) {
    return __uint_as_float(((unsigned)u) << 16);
}

// async global->LDS DMA, 16 B/lane; LDS dest is wave-uniform base + lane*16
__device__ __forceinline__ void async16(const void* g, void* lds) {
    __builtin_amdgcn_global_load_lds(
        (const __attribute__((address_space(1))) unsigned int*)g,
        (__attribute__((address_space(3))) unsigned int*)lds, 16, 0, 0);
}

// ---------------------------------------------------------------------------
// elementwise fp32 -> bf16 cast, float4-vectorized
// ---------------------------------------------------------------------------
__global__ __launch_bounds__(256)
void cast_bf16_kernel_v2(const float* __restrict__ in,
                         unsigned short* __restrict__ out, int n4)
{
    int i = blockIdx.x * 256 + threadIdx.x;
    if (i < n4) {
        float4 v = ((const float4*)in)[i];
        ushort4 o;
        o.x = f2bf(v.x); o.y = f2bf(v.y); o.z = f2bf(v.z); o.w = f2bf(v.w);
        ((ushort4*)out)[i] = o;
    }
}

// ---------------------------------------------------------------------------
// W (K x N fp32 row-major) -> Wt (N x K bf16 row-major), 32x32 LDS tiles
// ---------------------------------------------------------------------------
__global__ __launch_bounds__(256)
void transpose_cast_kernel_v2(const float* __restrict__ W,
                              unsigned short* __restrict__ Wt, int K, int N)
{
    __shared__ float tile[32][33];
    const int tx = threadIdx.x & 31, ty = threadIdx.x >> 5;  // ty in 0..7
    const int n0 = blockIdx.x * 32, k0 = blockIdx.y * 32;
#pragma unroll
    for (int r = 0; r < 4; r++)
        tile[ty + 8 * r][tx] = W[(size_t)(k0 + ty + 8 * r) * N + n0 + tx];
    __syncthreads();
#pragma unroll
    for (int r = 0; r < 4; r++)
        Wt[(size_t)(n0 + ty + 8 * r) * K + k0 + tx] = f2bf(tile[tx][ty + 8 * r]);
}

// ---------------------------------------------------------------------------
// V (bh, l, dh) -> Vt (bh, dh, l), bf16, 32x32 LDS tiles (+2B pad row)
// ---------------------------------------------------------------------------
__global__ __launch_bounds__(256)
void transpose_v_kernel_v2(const unsigned short* __restrict__ Vb,
                           unsigned short* __restrict__ VtG)
{
    __shared__ unsigned short tile[32][34];
    const int tx = threadIdx.x & 31, ty = threadIdx.x >> 5;
    const int l0 = blockIdx.x * 32, d0 = blockIdx.y * 32;
    const int bh = blockIdx.z;
    const unsigned short* src = Vb + (size_t)bh * LL * DH;
    unsigned short* dst = VtG + (size_t)bh * DH * LL;
#pragma unroll
    for (int r = 0; r < 4; r++)
        tile[ty + 8 * r][tx] = src[(size_t)(l0 + ty + 8 * r) * DH + d0 + tx];
    __syncthreads();
#pragma unroll
    for (int r = 0; r < 4; r++)
        dst[(size_t)(d0 + ty + 8 * r) * LL + l0 + tx] = tile[tx][ty + 8 * r];
}

// ---------------------------------------------------------------------------
// bf16 MFMA GEMM, m97 structure: C(MxN) = A(MxK) * Bt(NxK)^T.
// 128x128 block tile, BK=32, 4 waves each owning a 64x64 quadrant.
// MODE 0: fp32 store to C. MODE 1: bf16 scatter to Q/K/V in (B,H,L,Dh).
// ---------------------------------------------------------------------------
template<int N, int MODE>
__global__ __launch_bounds__(256)
void mfma_gemm_v2(const unsigned short* __restrict__ A,
                  const unsigned short* __restrict__ Bt,
                  float* __restrict__ C, unsigned short* __restrict__ Qo,
                  unsigned short* __restrict__ Ko, unsigned short* __restrict__ Vo)
{
    __shared__ unsigned short As[128 * 32];   // [m][k] contiguous (DMA order)
    __shared__ unsigned short Bs[128 * 32];   // [n][k] contiguous
    const int t = threadIdx.x;
    const int w = t >> 6, lane = t & 63;
    const int lrow = lane & 15, quad = lane >> 4;
    const int m0 = blockIdx.y * 128, n0 = blockIdx.x * 128;
    const int wm = (w >> 1) * 64, wn = (w & 1) * 64;

    floatx4 acc[4][4];
#pragma unroll
    for (int i = 0; i < 4; i++)
#pragma unroll
        for (int j = 0; j < 4; j++) acc[i][j] = (floatx4){0.f, 0.f, 0.f, 0.f};

    const int srow = 32 * w + (lane >> 2);
    const int sseg = (lane & 3) * 8;

    for (int k0 = 0; k0 < KDIM; k0 += 32) {
        __syncthreads();
        async16(&A [(size_t)(m0 + srow)      * KDIM + k0 + sseg], &As[(32 * w)      * 32]);
        async16(&A [(size_t)(m0 + srow + 16) * KDIM + k0 + sseg], &As[(32 * w + 16) * 32]);
        async16(&Bt[(size_t)(n0 + srow)      * KDIM + k0 + sseg], &Bs[(32 * w)      * 32]);
        async16(&Bt[(size_t)(n0 + srow + 16) * KDIM + k0 + sseg], &Bs[(32 * w + 16) * 32]);
        __syncthreads();

        short8 a[4], b[4];
#pragma unroll
        for (int i = 0; i < 4; i++)
            a[i] = *(const short8*)&As[(wm + i * 16 + lrow) * 32 + quad * 8];
#pragma unroll
        for (int j = 0; j < 4; j++)
            b[j] = *(const short8*)&Bs[(wn + j * 16 + lrow) * 32 + quad * 8];
#pragma unroll
        for (int i = 0; i < 4; i++)
#pragma unroll
            for (int j = 0; j < 4; j++)
                acc[i][j] = __builtin_amdgcn_mfma_f32_16x16x32_bf16(a[i], b[j], acc[i][j], 0, 0, 0);
    }

    // C/D fragment layout: col = lane&15, row = quad*4 + reg (m89-verified)
    if (MODE == 0) {
#pragma unroll
        for (int i = 0; i < 4; i++)
#pragma unroll
            for (int j = 0; j < 4; j++) {
                int col = n0 + wn + j * 16 + lrow;
#pragma unroll
                for (int r = 0; r < 4; r++) {
                    int m = m0 + wm + i * 16 + quad * 4 + r;
                    C[(size_t)m * N + col] = acc[i][j][r];
                }
            }
    } else {
        const int s = n0 >> 11;              // qkv slot, uniform per block
        const int h = (n0 & 2047) >> 7;
        unsigned short* dst = (s == 0) ? Qo : (s == 1) ? Ko : Vo;
#pragma unroll
        for (int i = 0; i < 4; i++)
#pragma unroll
            for (int j = 0; j < 4; j++) {
                int dh = wn + j * 16 + lrow;
#pragma unroll
                for (int r = 0; r < 4; r++) {
                    int m = m0 + wm + i * 16 + quad * 4 + r;
                    int b = m >> 11, l = m & 2047;
                    dst[(((size_t)b * NH + h) * LL + l) * DH + dh] = f2bf(acc[i][j][r]);
                }
            }
    }
}

// ---------------------------------------------------------------------------
// RoPE + L2-normalize, in place on bf16 Q/K (fp32 internal); Q *= s_qk.
// One 128-thread block per (bh, l).
// ---------------------------------------------------------------------------
__global__ __launch_bounds__(128)
void rope_norm_kernel_v2(unsigned short* __restrict__ Q,
                         unsigned short* __restrict__ K,
                         const float* __restrict__ s_qk_ptr)
{
    const int l  = blockIdx.x;
    const int bh = blockIdx.y;
    const int d  = threadIdx.x;
    __shared__ float sh[128];

    const size_t base = ((size_t)bh * LL + l) * DH + d;
    float qv = bf2f(Q[base]);
    float kv = bf2f(K[base]);

    const int i = d & 63;
    // inv_freq = 10000^(-i/64); ln(10000)/64 = 0.14391156831
    float ang = (float)l * expf(-0.14391157f * (float)i);
    float c = cosf(ang), s = sinf(ang);

    sh[d] = qv; __syncthreads();
    float qrot = (d < 64) ? -sh[d + 64] : sh[d - 64];
    float qr = fmaf(qv, c, qrot * s);
    __syncthreads();

    sh[d] = kv; __syncthreads();
    float krot = (d < 64) ? -sh[d + 64] : sh[d - 64];
    float kr = fmaf(kv, c, krot * s);
    __syncthreads();

    sh[d] = qr * qr; __syncthreads();
    for (int st = 64; st > 0; st >>= 1) {
        if (d < st) sh[d] += sh[d + st];
        __syncthreads();
    }
    float qn = sqrtf(sh[0]);
    __syncthreads();

    sh[d] = kr * kr; __syncthreads();
    for (int st = 64; st > 0; st >>= 1) {
        if (d < st) sh[d] += sh[d + st];
        __syncthreads();
    }
    float kn = sqrtf(sh[0]);

    float sqk = s_qk_ptr[0];
    Q[base] = f2bf(qr / fmaxf(qn, 1e-12f) * sqk);
    K[base] = f2bf(kr / fmaxf(kn, 1e-12f));
}

// ---------------------------------------------------------------------------
// bf16 MFMA flash attention, causal. BQ=64 (4 waves x 16 rows), BK=64.
// K staged [key][d]; V staged pre-transposed [d][key]; both via async DMA.
// Softmax in registers via 16-lane shfl_xor; P crosses C->A layout through
// per-wave padded LDS. Output written bf16 into (B, L, D).
// ---------------------------------------------------------------------------
#define ABQ 64
#define ABK 64
__global__ __launch_bounds__(256)
void attn_mfma_kernel_v2(const unsigned short* __restrict__ Q,
                         const unsigned short* __restrict__ K,
                         const unsigned short* __restrict__ Vt,
                         unsigned short* __restrict__ AOb)
{
    __shared__ __align__(16) unsigned short Ks[ABK * DH];      // 16 KB
    __shared__ __align__(16) unsigned short Vs[DH * ABK];      // 16 KB
    __shared__ __align__(16) unsigned short Ps[4][16][72];     // ~9 KB padded

    const int t = threadIdx.x;
    const int w = t >> 6, lane = t & 63;
    const int lrow = lane & 15, quad = lane >> 4;
    const int bh = blockIdx.y;
    const int qt = gridDim.x - 1 - blockIdx.x;   // heavy q-tiles first
    const int q0 = qt * ABQ;
    const int qw = q0 + w * 16;                  // wave's first q-row

    const unsigned short* Qb = Q  + (size_t)bh * LL * DH;
    const unsigned short* Kb = K  + (size_t)bh * LL * DH;
    const unsigned short* Vg = Vt + (size_t)bh * DH * LL;

    // Q A-fragments: row = lrow, k = kk*32 + quad*8 + j
    short8 aq[4];
#pragma unroll
    for (int kk = 0; kk < 4; kk++)
        aq[kk] = *(const short8*)&Qb[(size_t)(qw + lrow) * DH + kk * 32 + quad * 8];

    floatx4 oacc[8];
#pragma unroll
    for (int dt = 0; dt < 8; dt++) oacc[dt] = (floatx4){0.f, 0.f, 0.f, 0.f};
    float mrow[4] = {-1e30f, -1e30f, -1e30f, -1e30f};
    float lsum[4] = {0.f, 0.f, 0.f, 0.f};

    const int ntiles = qt + 1;
    for (int tile = 0; tile < ntiles; tile++) {
        const int k0 = tile * ABK;
        __syncthreads();
        // K tile: wave w stages key-rows 16w..16w+15 (256 B rows, 4/call)
#pragma unroll
        for (int c = 0; c < 4; c++) {
            int row = 16 * w + 4 * c;
            async16(&Kb[(size_t)(k0 + row + (lane >> 4)) * DH + (lane & 15) * 8],
                    &Ks[row * DH]);
        }
        // V^T tile: wave w stages d-rows 32w..32w+31 (128 B rows, 8/call)
#pragma unroll
        for (int c = 0; c < 4; c++) {
            int row = 32 * w + 8 * c;
            async16(&Vg[(size_t)(row + (lane >> 3)) * LL + k0 + (lane & 7) * 8],
                    &Vs[row * ABK]);
        }
        __syncthreads();

        // S = Q K^T; sacc[j] holds keys j*16..j*16+15 for rows qw+quad*4+r
        floatx4 sacc[4];
#pragma unroll
        for (int j = 0; j < 4; j++) sacc[j] = (floatx4){0.f, 0.f, 0.f, 0.f};
#pragma unroll
        for (int kk = 0; kk < 4; kk++) {
#pragma unroll
            for (int j = 0; j < 4; j++) {
                short8 bk = *(const short8*)&Ks[(j * 16 + lrow) * DH + kk * 32 + quad * 8];
                sacc[j] = __builtin_amdgcn_mfma_f32_16x16x32_bf16(aq[kk], bk, sacc[j], 0, 0, 0);
            }
        }

        // causal mask: required when max key in tile > wave's MIN q-row (qw).
        // (Earlier bug compared against qw+15, leaving wave 3's diagonal
        // tile unmasked.) Fires only on the diagonal tile.
        if (k0 + ABK - 1 > qw) {
#pragma unroll
            for (int j = 0; j < 4; j++) {
                int key = k0 + j * 16 + lrow;
#pragma unroll
                for (int r = 0; r < 4; r++) {
                    int q = qw + quad * 4 + r;
                    if (key > q) sacc[j][r] = -1e30f;
                }
            }
        }

        // online softmax; each row's 16 scores live across a 16-lane group
        float alpha[4];
#pragma unroll
        for (int r = 0; r < 4; r++) {
            float mt = fmaxf(fmaxf(sacc[0][r], sacc[1][r]),
                             fmaxf(sacc[2][r], sacc[3][r]));
#pragma unroll
            for (int off = 1; off < 16; off <<= 1)
                mt = fmaxf(mt, __shfl_xor(mt, off, 16));
            float mn = fmaxf(mrow[r], mt);
            alpha[r] = __expf(mrow[r] - mn);
            mrow[r] = mn;
        }
        // P = exp(S - m): stage bf16 into per-wave LDS; reduce row sums
#pragma unroll
        for (int r = 0; r < 4; r++) {
            float rs = 0.f;
#pragma unroll
            for (int j = 0; j < 4; j++) {
                float p = __expf(sacc[j][r] - mrow[r]);
                rs += p;
                Ps[w][quad * 4 + r][j * 16 + lrow] = f2bf(p);
            }
#pragma unroll
            for (int off = 1; off < 16; off <<= 1)
                rs += __shfl_xor(rs, off, 16);
            lsum[r] = lsum[r] * alpha[r] + rs;
        }

        // O = O*alpha + P @ V
#pragma unroll
        for (int dt = 0; dt < 8; dt++)
#pragma unroll
            for (int r = 0; r < 4; r++) oacc[dt][r] *= alpha[r];
#pragma unroll
        for (int kk2 = 0; kk2 < 2; kk2++) {
            short8 pa = *(const short8*)&Ps[w][lrow][kk2 * 32 + quad * 8];
#pragma unroll
            for (int dt = 0; dt < 8; dt++) {
                short8 bv = *(const short8*)&Vs[(dt * 16 + lrow) * ABK + kk2 * 32 + quad * 8];
                oacc[dt] = __builtin_amdgcn_mfma_f32_16x16x32_bf16(pa, bv, oacc[dt], 0, 0, 0);
            }
        }
    }

    // epilogue: divide by row sum, store bf16 to (B, L, D)
    const int b = bh >> 4, h = bh & 15;
#pragma unroll
    for (int r = 0; r < 4; r++) {
        float inv = 1.f / lsum[r];
        int q = qw + quad * 4 + r;
        size_t base = ((size_t)b * LL + q) * D + h * DH;
#pragma unroll
        for (int dt = 0; dt < 8; dt++)
            AOb[base + dt * 16 + lrow] = f2bf(oacc[dt][r] * inv);
    }
}

// ---------------------------------------------------------------------------
extern "C" void kernel_launch(void* const* d_in, const int* in_sizes, int n_in,
                              void* d_out, int out_size, void* d_ws, size_t ws_size,
                              hipStream_t stream)
{
    const float* x     = (const float*)d_in[0];
    const float* w_qkv = (const float*)d_in[1];
    const float* w_out = (const float*)d_in[2];
    const float* s_qk  = (const float*)d_in[3];
    float* out = (float*)d_out;

    const size_t SZ = (size_t)BB * NH * LL * DH;   // 8388608 elements
    unsigned short* u = (unsigned short*)d_ws;
    unsigned short* xb    = u;                               // x bf16 -> later AO bf16
    unsigned short* wqkvT = xb    + (size_t)MROWS * KDIM;    // 6144 x 2048
    unsigned short* woutT = wqkvT + (size_t)(3 * D) * KDIM;  // 2048 x 2048
    unsigned short* Qb    = woutT + (size_t)D * KDIM;
    unsigned short* Kb    = Qb + SZ;
    unsigned short* Vb    = Kb + SZ;
    unsigned short* VtG   = Vb + SZ;

    // 1) x -> bf16
    cast_bf16_kernel_v2<<<(MROWS * KDIM / 4 + 255) / 256, 256, 0, stream>>>(
        x, xb, MROWS * KDIM / 4);
    // 2) w_qkv -> (3D x K) bf16
    transpose_cast_kernel_v2<<<dim3(3 * D / 32, KDIM / 32), 256, 0, stream>>>(
        w_qkv, wqkvT, KDIM, 3 * D);
    // 3) QKV projection, bf16 scatter into (B,H,L,Dh)
    mfma_gemm_v2<3 * D, 1><<<dim3(3 * D / 128, MROWS / 128), 256, 0, stream>>>(
        xb, wqkvT, nullptr, Qb, Kb, Vb);
    // 4) RoPE + normalize in place (+ s_qk into Q)
    rope_norm_kernel_v2<<<dim3(LL, BHD), 128, 0, stream>>>(Qb, Kb, s_qk);
    // 5) V -> V^T (bh, dh, l)
    transpose_v_kernel_v2<<<dim3(LL / 32, DH / 32, BHD), 256, 0, stream>>>(Vb, VtG);
    // 6) flash attention -> AO bf16 (B,L,D), reusing xb
    attn_mfma_kernel_v2<<<dim3(LL / ABQ, BHD), 256, 0, stream>>>(Qb, Kb, VtG, xb);
    // 7) w_out -> bf16
    transpose_cast_kernel_v2<<<dim3(D / 32, D / 32), 256, 0, stream>>>(
        w_out, woutT, D, D);
    // 8) output projection
    mfma_gemm_v2<D, 0><<<dim3(D / 128, MROWS / 128), 256, 0, stream>>>(
        xb, woutT, out, nullptr, nullptr, nullptr);
}